// Round 6
// baseline (564.799 us; speedup 1.0000x reference)
//
#include <hip/hip_runtime.h>

// Problem constants (B,T,U,D,V) = (2,512,128,512,1024)
#define BB 2
#define TT 512
#define UU 128
#define DD 512
#define VV 1024

typedef float float4v __attribute__((ext_vector_type(4)));
typedef float f32x4   __attribute__((ext_vector_type(4)));
typedef short short8  __attribute__((ext_vector_type(8)));

__device__ __forceinline__ unsigned short f2bf(float f) {
    unsigned u = __builtin_bit_cast(unsigned, f);
    unsigned r = (u + 0x7FFFu + ((u >> 16) & 1u)) >> 16;   // RNE
    return (unsigned short)r;
}

__device__ __forceinline__ short8 pack_bf16_8(float4v lo, float4v hi) {
    short8 r;
    r[0] = (short)f2bf(lo.x); r[1] = (short)f2bf(lo.y);
    r[2] = (short)f2bf(lo.z); r[3] = (short)f2bf(lo.w);
    r[4] = (short)f2bf(hi.x); r[5] = (short)f2bf(hi.y);
    r[6] = (short)f2bf(hi.z); r[7] = (short)f2bf(hi.w);
    return r;
}

// ---------------------------------------------------------------------------
// Kernel 1: dec projection only (tiny): Cdec[m][v] = sum_k Dec[m][k]*W[v][512+k]
// 64 blocks (4 x 16 tiles of 64x64), proven MFMA structure from rounds 2-5.
// ---------------------------------------------------------------------------
__global__ __launch_bounds__(256) void dec_gemm_mfma(
    const float* __restrict__ Adec,
    const float* __restrict__ W,
    float* __restrict__ Cdec)
{
    __shared__ alignas(16) unsigned short sA[64][40];
    __shared__ alignas(16) unsigned short sB[64][40];

    const int tile_m = blockIdx.x >> 4;   // 0..3
    const int tile_n = blockIdx.x & 15;   // 0..15
    const int row0 = tile_m * 64;
    const int col0 = tile_n * 64;
    const float* Wp = W + DD;             // dec uses W[:, 512:]

    const int tid  = threadIdx.x;
    const int lane = tid & 63;
    const int wave = tid >> 6;
    const int wr   = wave >> 1;
    const int wc   = wave & 1;
    const int lrow = lane & 15;
    const int kg   = lane >> 4;
    const int srow = tid >> 2;
    const int schk = tid & 3;

    f32x4 acc[2][2] = {};

    for (int k0 = 0; k0 < DD; k0 += 32) {
        const float* ap = &Adec[(size_t)(row0 + srow) * DD     + k0 + schk * 8];
        const float* wp = &Wp  [(size_t)(col0 + srow) * (2*DD) + k0 + schk * 8];
        float4v a0 = *(const float4v*)ap;
        float4v a1 = *(const float4v*)(ap + 4);
        float4v w0 = *(const float4v*)wp;
        float4v w1 = *(const float4v*)(wp + 4);
        short8 av = pack_bf16_8(a0, a1);
        short8 wv = pack_bf16_8(w0, w1);

        __syncthreads();
        *(short8*)&sA[srow][schk * 8] = av;
        *(short8*)&sB[srow][schk * 8] = wv;
        __syncthreads();

        short8 af0 = *(const short8*)&sA[wr * 32 +      lrow][kg * 8];
        short8 af1 = *(const short8*)&sA[wr * 32 + 16 + lrow][kg * 8];
        short8 bf0 = *(const short8*)&sB[wc * 32 +      lrow][kg * 8];
        short8 bf1 = *(const short8*)&sB[wc * 32 + 16 + lrow][kg * 8];

        acc[0][0] = __builtin_amdgcn_mfma_f32_16x16x32_bf16(af0, bf0, acc[0][0], 0, 0, 0);
        acc[0][1] = __builtin_amdgcn_mfma_f32_16x16x32_bf16(af0, bf1, acc[0][1], 0, 0, 0);
        acc[1][0] = __builtin_amdgcn_mfma_f32_16x16x32_bf16(af1, bf0, acc[1][0], 0, 0, 0);
        acc[1][1] = __builtin_amdgcn_mfma_f32_16x16x32_bf16(af1, bf1, acc[1][1], 0, 0, 0);
    }

    // C/D layout (HW-verified): col = lane&15, row = (lane>>4)*4 + reg
    #pragma unroll
    for (int mi = 0; mi < 2; ++mi)
        #pragma unroll
        for (int ni = 0; ni < 2; ++ni) {
            const int r0 = row0 + wr * 32 + mi * 16 + kg * 4;
            const int c  = col0 + wc * 32 + ni * 16 + lrow;
            #pragma unroll
            for (int j = 0; j < 4; ++j)
                Cdec[(size_t)(r0 + j) * VV + c] = acc[mi][ni][j];
        }
}

// ---------------------------------------------------------------------------
// Kernel 2: FUSED enc-GEMM + broadcast write.
// Each block: (a) MFMA-computes a 64x64 enc_proj tile (rows = b*T+t composite,
// cols = v), (b) stages it f32 in LDS [64][68], (c) writes its 64t x 128u x 64v
// output slab: out[row,u,v] = tile[t][v] + dec_proj[b,u,v]. NT float4 stores,
// 256B-contiguous segments (2 full cache lines). Grid 256 blocks = 16x16 tiles.
// ---------------------------------------------------------------------------
__global__ __launch_bounds__(256) void enc_gemm_bcast(
    const float* __restrict__ Aenc,
    const float* __restrict__ W,
    const float* __restrict__ dec_proj,
    float* __restrict__ out)
{
    __shared__ alignas(16) unsigned short sA[64][40];
    __shared__ alignas(16) unsigned short sB[64][40];
    __shared__ alignas(16) float sT[64][68];

    const int tile_m = blockIdx.x >> 4;   // 0..15 (rows of b*T+t)
    const int tile_n = blockIdx.x & 15;   // 0..15 (v)
    const int row0 = tile_m * 64;
    const int col0 = tile_n * 64;

    const int tid  = threadIdx.x;
    const int lane = tid & 63;
    const int wave = tid >> 6;
    const int wr   = wave >> 1;
    const int wc   = wave & 1;
    const int lrow = lane & 15;
    const int kg   = lane >> 4;
    const int srow = tid >> 2;
    const int schk = tid & 3;

    f32x4 acc[2][2] = {};

    for (int k0 = 0; k0 < DD; k0 += 32) {
        const float* ap = &Aenc[(size_t)(row0 + srow) * DD     + k0 + schk * 8];
        const float* wp = &W   [(size_t)(col0 + srow) * (2*DD) + k0 + schk * 8];
        float4v a0 = *(const float4v*)ap;
        float4v a1 = *(const float4v*)(ap + 4);
        float4v w0 = *(const float4v*)wp;
        float4v w1 = *(const float4v*)(wp + 4);
        short8 av = pack_bf16_8(a0, a1);
        short8 wv = pack_bf16_8(w0, w1);

        __syncthreads();
        *(short8*)&sA[srow][schk * 8] = av;
        *(short8*)&sB[srow][schk * 8] = wv;
        __syncthreads();

        short8 af0 = *(const short8*)&sA[wr * 32 +      lrow][kg * 8];
        short8 af1 = *(const short8*)&sA[wr * 32 + 16 + lrow][kg * 8];
        short8 bf0 = *(const short8*)&sB[wc * 32 +      lrow][kg * 8];
        short8 bf1 = *(const short8*)&sB[wc * 32 + 16 + lrow][kg * 8];

        acc[0][0] = __builtin_amdgcn_mfma_f32_16x16x32_bf16(af0, bf0, acc[0][0], 0, 0, 0);
        acc[0][1] = __builtin_amdgcn_mfma_f32_16x16x32_bf16(af0, bf1, acc[0][1], 0, 0, 0);
        acc[1][0] = __builtin_amdgcn_mfma_f32_16x16x32_bf16(af1, bf0, acc[1][0], 0, 0, 0);
        acc[1][1] = __builtin_amdgcn_mfma_f32_16x16x32_bf16(af1, bf1, acc[1][1], 0, 0, 0);
    }

    // stage tile into LDS (local t, local v); C/D layout col=lane&15, row=(lane>>4)*4+reg
    #pragma unroll
    for (int mi = 0; mi < 2; ++mi)
        #pragma unroll
        for (int ni = 0; ni < 2; ++ni) {
            const int r0 = wr * 32 + mi * 16 + kg * 4;
            const int c  = wc * 32 + ni * 16 + lrow;
            #pragma unroll
            for (int j = 0; j < 4; ++j)
                sT[r0 + j][c] = acc[mi][ni][j];
        }
    __syncthreads();

    // broadcast-write phase
    const int vq = tid & 15;          // v-quad: v = vq*4 (local)
    const int pr = tid >> 4;          // 0..15: t-subrow within each 16-row group
    const int b  = row0 >> 9;         // 64 | 512 so whole tile shares b

    const float* dbase = dec_proj + ((size_t)b * UU) * VV + col0 + vq * 4;
    float* obase = out + ((size_t)(row0 + pr) * UU) * VV + col0 + vq * 4;
    const size_t tstep = (size_t)16 * UU * VV;   // +16 rows

    #pragma unroll 2
    for (int u = 0; u < UU; ++u) {
        float4v d = *(const float4v*)&dbase[(size_t)u * VV];
        float* op = obase + (size_t)u * VV;
        #pragma unroll
        for (int tr = 0; tr < 4; ++tr) {
            float4v e = *(const float4v*)&sT[tr * 16 + pr][vq * 4];
            __builtin_nontemporal_store(e + d, (float4v*)(op + tr * tstep));
        }
    }
}

extern "C" void kernel_launch(void* const* d_in, const int* in_sizes, int n_in,
                              void* d_out, int out_size, void* d_ws, size_t ws_size,
                              hipStream_t stream) {
    (void)in_sizes; (void)n_in; (void)out_size; (void)ws_size;
    const float* enc = (const float*)d_in[0];   // (2,512,512)  f32
    const float* dec = (const float*)d_in[1];   // (2,128,512)  f32
    const float* W   = (const float*)d_in[2];   // (1024,1024)  f32
    float* out = (float*)d_out;                 // (2,512,128,1024) f32

    float* dec_proj = (float*)d_ws;             // 256*1024 f32 = 1 MB

    dec_gemm_mfma<<<dim3(64),  dim3(256), 0, stream>>>(dec, W, dec_proj);
    enc_gemm_bcast<<<dim3(256), dim3(256), 0, stream>>>(enc, W, dec_proj, out);
}